// Round 9
// baseline (188.921 us; speedup 1.0000x reference)
//
#include <hip/hip_runtime.h>

#define BSZ 256
#define MAXA 8
#define CTXD 128
#define HID 512
#define STD 512
#define TACD 128
#define DEFN 20000
#define CVD 256
#define DIMQ 257
#define LNGW 2056   // MAX_ARGS*DIMQ

typedef __attribute__((ext_vector_type(8))) short bf16x8;
typedef __attribute__((ext_vector_type(4))) float f32x4;

// ---- ws layout ----
// int region
#define O_TOT 0
#define O_NP  1
#define O_CS  16      // ctx_start[257]
#define O_AS  288     // arg_start[257]
#define O_AB  560     // arg_batch[2048]
#define O_SL  2608    // arg_slot[2048]
#define O_PS  4656    // pair_start[2049]
// float region (offsets in floats)
#define F_GQ   8192     // GQB bf16 2048*128 (occupies 65536 float-slots; padded rows zeroed)
#define F_QB   272384    // 2048                -> 274432
#define F_ST   438272    // 256*512             -> 569344
#define F_LNG  569344    // 256*2056            -> 1095680
#define F_QK   1095680   // 2048*256            -> 1619968 floats = 6.48MB
#define F_GKB  274432    // bf16 gk: 20000*128*2B -> float-slots 274432..1585152 (overlays dead ST/LNG/QK)

__device__ __forceinline__ ushort f2bf(float f) {
    uint u = __float_as_uint(f);
    return (ushort)((u + 0x7FFFu + ((u >> 16) & 1u)) >> 16);
}

// parallel lower_bound table: for each b in [0,256], W[O_CS+b] = first i with ctx_ids[i] >= b
__global__ __launch_bounds__(256) void k_bounds(const int* __restrict__ ctx_ids, int n_ctx,
                                                int* __restrict__ W) {
    int i = blockIdx.x * 256 + threadIdx.x;
    if (i >= n_ctx) return;
    int cur = ctx_ids[i];
    int prev = (i == 0) ? -1 : ctx_ids[i - 1];
    for (int b = prev + 1; b <= cur; b++) W[O_CS + b] = i;
    if (i == n_ctx - 1) {
        for (int b = cur + 1; b <= BSZ; b++) W[O_CS + b] = n_ctx;
    }
}

// small scans over 256 entries (reads ctx starts from W)
__global__ __launch_bounds__(256) void k_scan(const int* __restrict__ arg_cnt, int* __restrict__ W) {
    __shared__ int s_start[BSZ + 1];
    __shared__ int s_len[BSZ];
    __shared__ int s_scan[BSZ];
    __shared__ int s_as[BSZ + 1];
    __shared__ int s_ab[2048];
    __shared__ int s_sl[2048];
    __shared__ int s_ps[BSZ];
    int tid = threadIdx.x;
    s_start[tid] = W[O_CS + tid];
    if (tid == 0) s_start[BSZ] = W[O_CS + BSZ];
    int c = arg_cnt[tid];
    s_scan[tid] = c;
    __syncthreads();
    s_len[tid] = s_start[tid + 1] - s_start[tid];
    for (int off = 1; off < BSZ; off <<= 1) {
        int v = s_scan[tid];
        int a = (tid >= off) ? s_scan[tid - off] : 0;
        __syncthreads();
        s_scan[tid] = v + a;
        __syncthreads();
    }
    int astart = s_scan[tid] - c;
    s_as[tid] = astart;
    if (tid == BSZ - 1) s_as[BSZ] = s_scan[tid];
    __syncthreads();
    int total = s_as[BSZ];
    for (int k = 0; k < c; k++) { s_ab[astart + k] = tid; s_sl[astart + k] = k; }
    __syncthreads();
    int base = tid * 8;
    int loc[8]; int run = 0;
    for (int j = 0; j < 8; j++) {
        int t = base + j;
        int l = (t < total) ? s_len[s_ab[t]] : 0;
        loc[j] = run; run += l;
    }
    s_ps[tid] = run;
    __syncthreads();
    for (int off = 1; off < BSZ; off <<= 1) {
        int v = s_ps[tid];
        int a = (tid >= off) ? s_ps[tid - off] : 0;
        __syncthreads();
        s_ps[tid] = v + a;
        __syncthreads();
    }
    int pbase = s_ps[tid] - run;
    int np = s_ps[BSZ - 1];
    W[O_AS + tid] = astart;
    if (tid == 0) { W[O_AS + BSZ] = total; W[O_TOT] = total; W[O_NP] = np; W[O_PS + 2048] = np; }
    for (int j = 0; j < 8; j++) {
        int t = base + j;
        W[O_PS + t] = pbase + loc[j];
        W[O_AB + t] = (t < total) ? s_ab[t] : 0;
        W[O_SL + t] = (t < total) ? s_sl[t] : 0;
    }
}

// st = relu([se|te] @ W_st + b_st).  M=256,N=512,K=640. 16x32 tile, BK=16, grid(16,16).
__global__ __launch_bounds__(256) void k_fc1(const float* __restrict__ se, const float* __restrict__ te,
                                             const float* __restrict__ B, const float* __restrict__ bias,
                                             float* __restrict__ C) {
    __shared__ float sA[16][17];
    __shared__ float sB[16][34];
    int tid = threadIdx.x;
    int c0 = blockIdx.x * 32, r0 = blockIdx.y * 16;
    int ar = tid >> 4, ak = tid & 15;        // A loader: 1 elem
    int bc = tid & 31, bk = tid >> 5;        // B loader: rows bk, bk+8
    int m = tid >> 4, n0 = (tid & 15) * 2;   // compute
    float acc0 = 0.f, acc1 = 0.f;

    float ra = se[(r0 + ar) * STD + ak];
    float rb0 = B[bk * 512 + c0 + bc];
    float rb1 = B[(bk + 8) * 512 + c0 + bc];
    sA[ak][ar] = ra; sB[bk][bc] = rb0; sB[bk + 8][bc] = rb1;
    __syncthreads();

    for (int kc = 16; kc < 640; kc += 16) {
        float na = (kc < 512) ? se[(r0 + ar) * STD + kc + ak]
                              : te[(r0 + ar) * TACD + kc - 512 + ak];
        float nb0 = B[(kc + bk) * 512 + c0 + bc];
        float nb1 = B[(kc + bk + 8) * 512 + c0 + bc];
        #pragma unroll
        for (int k = 0; k < 16; k++) {
            float a = sA[k][m];
            float2 b2 = *(const float2*)&sB[k][n0];
            acc0 += a * b2.x; acc1 += a * b2.y;
        }
        __syncthreads();
        sA[ak][ar] = na; sB[bk][bc] = nb0; sB[bk + 8][bc] = nb1;
        __syncthreads();
    }
    #pragma unroll
    for (int k = 0; k < 16; k++) {
        float a = sA[k][m];
        float2 b2 = *(const float2*)&sB[k][n0];
        acc0 += a * b2.x; acc1 += a * b2.y;
    }
    float2 bb = *(const float2*)&bias[c0 + n0];
    float2 v; v.x = fmaxf(acc0 + bb.x, 0.f); v.y = fmaxf(acc1 + bb.y, 0.f);
    *(float2*)&C[(r0 + m) * 512 + c0 + n0] = v;
}

// LNG = st @ W_q + b_q.  M=256,N=2056,K=512. 32x64 tile, 2x4 micro, BK=16, grid(33,8).
__global__ __launch_bounds__(256) void k_fc2(const float* __restrict__ A, const float* __restrict__ B,
                                             const float* __restrict__ bias, float* __restrict__ C) {
    __shared__ float sA[16][33];
    __shared__ float sB[16][68];
    int tid = threadIdx.x;
    int c0 = blockIdx.x * 64, r0 = blockIdx.y * 32;
    int ar = tid >> 3, ak = (tid & 7) * 2;   // A loader: float2
    int bc = tid & 63, bk0 = (tid >> 6) * 4; // B loader: 4 rows
    int mg = tid >> 4, ng = tid & 15;        // compute: rows mg, mg+16; cols ng*4..+3
    bool bok = (c0 + bc) < 2056;
    float acc[2][4] = {};

    float2 ra = *(const float2*)&A[(r0 + ar) * 512 + ak];
    float rb[4];
    #pragma unroll
    for (int j = 0; j < 4; j++) rb[j] = bok ? B[(bk0 + j) * 2056 + c0 + bc] : 0.f;
    sA[ak][ar] = ra.x; sA[ak + 1][ar] = ra.y;
    #pragma unroll
    for (int j = 0; j < 4; j++) sB[bk0 + j][bc] = rb[j];
    __syncthreads();

    for (int kc = 16; kc < 512; kc += 16) {
        float2 na = *(const float2*)&A[(r0 + ar) * 512 + kc + ak];
        float nb[4];
        #pragma unroll
        for (int j = 0; j < 4; j++) nb[j] = bok ? B[(kc + bk0 + j) * 2056 + c0 + bc] : 0.f;
        #pragma unroll
        for (int k = 0; k < 16; k++) {
            float a0 = sA[k][mg], a1 = sA[k][mg + 16];
            float4 b4 = *(const float4*)&sB[k][ng * 4];
            acc[0][0] += a0 * b4.x; acc[0][1] += a0 * b4.y; acc[0][2] += a0 * b4.z; acc[0][3] += a0 * b4.w;
            acc[1][0] += a1 * b4.x; acc[1][1] += a1 * b4.y; acc[1][2] += a1 * b4.z; acc[1][3] += a1 * b4.w;
        }
        __syncthreads();
        sA[ak][ar] = na.x; sA[ak + 1][ar] = na.y;
        #pragma unroll
        for (int j = 0; j < 4; j++) sB[bk0 + j][bc] = nb[j];
        __syncthreads();
    }
    #pragma unroll
    for (int k = 0; k < 16; k++) {
        float a0 = sA[k][mg], a1 = sA[k][mg + 16];
        float4 b4 = *(const float4*)&sB[k][ng * 4];
        acc[0][0] += a0 * b4.x; acc[0][1] += a0 * b4.y; acc[0][2] += a0 * b4.z; acc[0][3] += a0 * b4.w;
        acc[1][0] += a1 * b4.x; acc[1][1] += a1 * b4.y; acc[1][2] += a1 * b4.z; acc[1][3] += a1 * b4.w;
    }
    int c = c0 + ng * 4;
    if (c < 2056) {
        float4 bb = *(const float4*)&bias[c];
        #pragma unroll
        for (int i = 0; i < 2; i++) {
            float4 v;
            v.x = acc[i][0] + bb.x; v.y = acc[i][1] + bb.y;
            v.z = acc[i][2] + bb.z; v.w = acc[i][3] + bb.w;
            *(float4*)&C[(r0 + mg + 16 * i) * 2056 + c] = v;
        }
    }
}

// Per active arg t: split LNG row -> GQB(bf16) / none-logit (written straight to d_out);
// qk[t]=W_key@q_local, qb[t]=b_key.q_local.  Rows t in [total, 2048) get zero GQB (MFMA padding).
__global__ __launch_bounds__(256) void k_extract(const int* __restrict__ W, const float* __restrict__ LNG,
                                                 const float* __restrict__ Wkey, const float* __restrict__ bkey,
                                                 ushort* __restrict__ GQB, float* __restrict__ out, int L,
                                                 float* __restrict__ QK, float* __restrict__ QB) {
    int t = blockIdx.x;
    int total = W[O_TOT];
    int tid = threadIdx.x;
    if (t >= total) {
        if (tid >= 128) GQB[t * 128 + tid - 128] = 0;
        return;
    }
    int b = W[O_AB + t], slot = W[O_SL + t];
    const float* base = LNG + b * LNGW + slot * DIMQ;
    __shared__ float sl[CTXD];
    if (tid < 128) {
        sl[tid] = base[tid];
    } else {
        int d = tid - 128;
        GQB[t * 128 + d] = f2bf(base[129 + d]);
    }
    if (tid == 0) {
        int np = W[O_NP];
        out[np + t] = (float)t;
        out[L + np + t] = base[128];
    }
    __syncthreads();
    float acc = 0.f;
    const float* wr = Wkey + tid * 128;
    #pragma unroll
    for (int k = 0; k < 128; k += 4) {
        float4 w4 = *(const float4*)(wr + k);
        acc += w4.x * sl[k] + w4.y * sl[k + 1] + w4.z * sl[k + 2] + w4.w * sl[k + 3];
    }
    QK[t * 256 + tid] = acc;
    if (tid == 0) {
        float qb = 0.f;
        for (int k = 0; k < 128; k++) qb += bkey[k] * sl[k];
        QB[t] = qb;
    }
}

// gather + L2-normalize definition embeddings -> bf16 table in ws
__global__ __launch_bounds__(256) void k_gk(const int* __restrict__ gctx, const float* __restrict__ emb,
                                            ushort* __restrict__ gkb) {
    int tid = threadIdx.x;
    int g = blockIdx.x * 8 + (tid >> 5);
    int row = gctx[g];
    int c = tid & 31;
    float4 e = *(const float4*)(emb + (size_t)row * 128 + c * 4);
    float ss = e.x * e.x + e.y * e.y + e.z * e.z + e.w * e.w;
    #pragma unroll
    for (int off = 1; off < 32; off <<= 1) ss += __shfl_xor(ss, off);
    float sc = 1.f / (1e-7f + sqrtf(ss));
    ushort4 o;
    o.x = f2bf(e.x * sc); o.y = f2bf(e.y * sc); o.z = f2bf(e.z * sc); o.w = f2bf(e.w * sc);
    *(ushort4*)(gkb + (size_t)g * 128 + c * 4) = o;
}

// local logits: 4-lane groups, 16 rows/wave, QK staged in LDS (broadcast reads).
__global__ __launch_bounds__(256) void k_pairs(const int* __restrict__ W, const float* __restrict__ ctxv,
                                               const float* __restrict__ QK, const float* __restrict__ QB,
                                               float* __restrict__ out, int L) {
    int b = blockIdx.x >> 2, sub = blockIdx.x & 3;
    int as = W[O_AS + b];
    int cnt = W[O_AS + b + 1] - as;
    if (cnt == 0) return;
    int cs = W[O_CS + b];
    int len = W[O_CS + b + 1] - cs;
    int j0 = (len * sub) >> 2, j1 = (len * (sub + 1)) >> 2;
    __shared__ float sqk[MAXA][256];
    __shared__ float sqb[MAXA];
    __shared__ int sps[MAXA];
    int tid = threadIdx.x;
    for (int i = tid; i < cnt * 256; i += 256) sqk[i >> 8][i & 255] = QK[(as + (i >> 8)) * 256 + (i & 255)];
    if (tid < cnt) { sqb[tid] = QB[as + tid]; sps[tid] = W[O_PS + as + tid]; }
    __syncthreads();
    int wv = tid >> 6, lane = tid & 63;
    int g = lane >> 2, il = lane & 3;
    for (int jb = j0 + wv * 16; jb < j1; jb += 64) {
        int j = jb + g;
        bool ok = (j < j1);
        int row = cs + (ok ? j : j1 - 1);
        const float* xr = ctxv + (size_t)row * 256;
        float acc[MAXA] = {};
        #pragma unroll
        for (int c = 0; c < 16; c++) {
            float4 x4 = *(const float4*)(xr + c * 16 + il * 4);
            #pragma unroll
            for (int a = 0; a < MAXA; a++) {
                if (a < cnt) {
                    float4 q4 = *(const float4*)(&sqk[a][c * 16 + il * 4]);
                    acc[a] += x4.x * q4.x + x4.y * q4.y + x4.z * q4.z + x4.w * q4.w;
                }
            }
        }
        #pragma unroll
        for (int a = 0; a < MAXA; a++) {
            if (a < cnt) {
                float p = acc[a];
                p += __shfl_xor(p, 1);
                p += __shfl_xor(p, 2);
                if (il == 0 && ok) {
                    out[sps[a] + j] = (float)(as + a);
                    out[L + sps[a] + j] = p + sqb[a];
                }
            }
        }
    }
}

// global logits via bf16 MFMA. Block tile 32 args x 512 defs; 4 waves x 128 defs.
// Epilogue staged through LDS so each global store instruction writes 1KB CONTIGUOUS
// within one output row (store BW tracks fragments/instruction, measured R6-R8).
// Writes BOTH value plane and index plane (index = constant per row, no LDS needed).
__global__ __launch_bounds__(256) void k_gglob(const int* __restrict__ W, const ushort* __restrict__ GQB,
                                               const ushort* __restrict__ GKB, float* __restrict__ out, int L) {
    __shared__ float tile[32][516];   // stride 516: 16B-aligned rows, 2-way bank alias (free)
    int total = W[O_TOT], np = W[O_NP];
    int t0 = blockIdx.y * 32;
    if (t0 >= total) return;
    float* outi = out + np + total;
    float* outv = out + L + np + total;
    int gblk = blockIdx.x * 512;
    int tid = threadIdx.x, wv = tid >> 6, lane = tid & 63;
    int gw = wv * 128;
    int lhi = lane >> 4, llo = lane & 15;
    // B fragments (args): rows t0..t0+31 (zero-padded rows cover t >= total)
    bf16x8 bfr[2][4];
    #pragma unroll
    for (int ts = 0; ts < 2; ts++)
        #pragma unroll
        for (int kk = 0; kk < 4; kk++)
            bfr[ts][kk] = *(const bf16x8*)(GQB + (size_t)(t0 + ts * 16 + llo) * 128 + kk * 32 + lhi * 8);
    #pragma unroll
    for (int nt = 0; nt < 8; nt++) {
        int g = gblk + gw + nt * 16 + llo;
        const ushort* ap = GKB + (size_t)(g < DEFN ? g : DEFN - 1) * 128 + lhi * 8;
        bf16x8 afr[4];
        #pragma unroll
        for (int kk = 0; kk < 4; kk++) afr[kk] = *(const bf16x8*)(ap + kk * 32);
        f32x4 acc[2] = {};
        #pragma unroll
        for (int kk = 0; kk < 4; kk++)
            #pragma unroll
            for (int ts = 0; ts < 2; ts++)
                acc[ts] = __builtin_amdgcn_mfma_f32_16x16x32_bf16(afr[kk], bfr[ts][kk], acc[ts], 0, 0, 0);
        // D layout: col(=arg)=llo, row(=def)=lhi*4+reg  -> LDS
        int gs = gw + nt * 16 + lhi * 4;
        #pragma unroll
        for (int ts = 0; ts < 2; ts++)
            *(f32x4*)&tile[ts * 16 + llo][gs] = acc[ts];
    }
    __syncthreads();
    // store phase: wave wv streams rows wv*8 .. wv*8+7; 1KB contiguous per instruction
    #pragma unroll
    for (int r8 = 0; r8 < 8; r8++) {
        int r = wv * 8 + r8;
        int t = t0 + r;
        if (t >= total) break;
        size_t rb = (size_t)t * DEFN + gblk;
        float ft = (float)t;
        f32x4 fi = {ft, ft, ft, ft};
        int c = lane * 4;
        if (gblk + c < DEFN) {
            *(f32x4*)(outv + rb + c) = *(const f32x4*)&tile[r][c];
            *(f32x4*)(outi + rb + c) = fi;
        }
        c += 256;
        if (gblk + c < DEFN) {
            *(f32x4*)(outv + rb + c) = *(const f32x4*)&tile[r][c];
            *(f32x4*)(outi + rb + c) = fi;
        }
    }
}

extern "C" void kernel_launch(void* const* d_in, const int* in_sizes, int n_in,
                              void* d_out, int out_size, void* d_ws, size_t ws_size,
                              hipStream_t stream) {
    const float* ctx_vals  = (const float*)d_in[0];
    const float* state_emb = (const float*)d_in[1];
    const float* tactic    = (const float*)d_in[2];
    const float* emb       = (const float*)d_in[3];
    const float* W_key     = (const float*)d_in[4];
    const float* b_key     = (const float*)d_in[5];
    const float* W_st      = (const float*)d_in[6];
    const float* b_st      = (const float*)d_in[7];
    const float* W_q       = (const float*)d_in[8];
    const float* b_q       = (const float*)d_in[9];
    const int* ctx_ids     = (const int*)d_in[10];
    const int* arg_cnt     = (const int*)d_in[11];
    const int* gctx        = (const int*)d_in[12];
    int n_ctx = in_sizes[10];
    int L = out_size / 2;
    int* W  = (int*)d_ws;
    float* F = (float*)d_ws;
    float* out = (float*)d_out;

    k_bounds<<<dim3((n_ctx + 255) / 256), dim3(256), 0, stream>>>(ctx_ids, n_ctx, W);
    k_scan<<<dim3(1), dim3(256), 0, stream>>>(arg_cnt, W);
    k_fc1<<<dim3(16, 16), dim3(256), 0, stream>>>(state_emb, tactic, W_st, b_st, F + F_ST);
    k_fc2<<<dim3(33, 8), dim3(256), 0, stream>>>(F + F_ST, W_q, b_q, F + F_LNG);
    k_extract<<<dim3(2048), dim3(256), 0, stream>>>(W, F + F_LNG, W_key, b_key,
                                                    (ushort*)(F + F_GQ), out, L, F + F_QK, F + F_QB);
    k_pairs<<<dim3(1024), dim3(256), 0, stream>>>(W, ctx_vals, F + F_QK, F + F_QB, out, L);
    k_gk<<<dim3(2500), dim3(256), 0, stream>>>(gctx, emb, (ushort*)(F + F_GKB));
    k_gglob<<<dim3(40, 64), dim3(256), 0, stream>>>(W, (ushort*)(F + F_GQ), (ushort*)(F + F_GKB), out, L);
}

// Round 10
// 180.225 us; speedup vs baseline: 1.0482x; 1.0482x over previous
//
#include <hip/hip_runtime.h>

#define BSZ 256
#define MAXA 8
#define CTXD 128
#define HID 512
#define STD 512
#define TACD 128
#define DEFN 20000
#define CVD 256
#define DIMQ 257
#define LNGW 2056   // MAX_ARGS*DIMQ

typedef __attribute__((ext_vector_type(8))) short bf16x8;
typedef __attribute__((ext_vector_type(4))) float f32x4;

// ---- ws layout ----
// int region
#define O_TOT 0
#define O_NP  1
#define O_CS  16      // ctx_start[257]
#define O_AS  288     // arg_start[257]
#define O_AB  560     // arg_batch[2048]
#define O_SL  2608    // arg_slot[2048]
#define O_PS  4656    // pair_start[2049]
// float region (offsets in floats)
#define F_GQ   8192     // GQB bf16 2048*128 (occupies 65536 float-slots; padded rows zeroed)
#define F_QB   272384    // 2048                -> 274432
#define F_ST   438272    // 256*512             -> 569344
#define F_LNG  569344    // 256*2056            -> 1095680
#define F_QK   1095680   // 2048*256            -> 1619968 floats = 6.48MB
#define F_GKB  274432    // bf16 gk: 20000*128*2B -> float-slots 274432..1585152 (overlays dead ST/LNG/QK)

__device__ __forceinline__ ushort f2bf(float f) {
    uint u = __float_as_uint(f);
    return (ushort)((u + 0x7FFFu + ((u >> 16) & 1u)) >> 16);
}

// parallel lower_bound table: for each b in [0,256], W[O_CS+b] = first i with ctx_ids[i] >= b
__global__ __launch_bounds__(256) void k_bounds(const int* __restrict__ ctx_ids, int n_ctx,
                                                int* __restrict__ W) {
    int i = blockIdx.x * 256 + threadIdx.x;
    if (i >= n_ctx) return;
    int cur = ctx_ids[i];
    int prev = (i == 0) ? -1 : ctx_ids[i - 1];
    for (int b = prev + 1; b <= cur; b++) W[O_CS + b] = i;
    if (i == n_ctx - 1) {
        for (int b = cur + 1; b <= BSZ; b++) W[O_CS + b] = n_ctx;
    }
}

// small scans over 256 entries (reads ctx starts from W)
__global__ __launch_bounds__(256) void k_scan(const int* __restrict__ arg_cnt, int* __restrict__ W) {
    __shared__ int s_start[BSZ + 1];
    __shared__ int s_len[BSZ];
    __shared__ int s_scan[BSZ];
    __shared__ int s_as[BSZ + 1];
    __shared__ int s_ab[2048];
    __shared__ int s_sl[2048];
    __shared__ int s_ps[BSZ];
    int tid = threadIdx.x;
    s_start[tid] = W[O_CS + tid];
    if (tid == 0) s_start[BSZ] = W[O_CS + BSZ];
    int c = arg_cnt[tid];
    s_scan[tid] = c;
    __syncthreads();
    s_len[tid] = s_start[tid + 1] - s_start[tid];
    for (int off = 1; off < BSZ; off <<= 1) {
        int v = s_scan[tid];
        int a = (tid >= off) ? s_scan[tid - off] : 0;
        __syncthreads();
        s_scan[tid] = v + a;
        __syncthreads();
    }
    int astart = s_scan[tid] - c;
    s_as[tid] = astart;
    if (tid == BSZ - 1) s_as[BSZ] = s_scan[tid];
    __syncthreads();
    int total = s_as[BSZ];
    for (int k = 0; k < c; k++) { s_ab[astart + k] = tid; s_sl[astart + k] = k; }
    __syncthreads();
    int base = tid * 8;
    int loc[8]; int run = 0;
    for (int j = 0; j < 8; j++) {
        int t = base + j;
        int l = (t < total) ? s_len[s_ab[t]] : 0;
        loc[j] = run; run += l;
    }
    s_ps[tid] = run;
    __syncthreads();
    for (int off = 1; off < BSZ; off <<= 1) {
        int v = s_ps[tid];
        int a = (tid >= off) ? s_ps[tid - off] : 0;
        __syncthreads();
        s_ps[tid] = v + a;
        __syncthreads();
    }
    int pbase = s_ps[tid] - run;
    int np = s_ps[BSZ - 1];
    W[O_AS + tid] = astart;
    if (tid == 0) { W[O_AS + BSZ] = total; W[O_TOT] = total; W[O_NP] = np; W[O_PS + 2048] = np; }
    for (int j = 0; j < 8; j++) {
        int t = base + j;
        W[O_PS + t] = pbase + loc[j];
        W[O_AB + t] = (t < total) ? s_ab[t] : 0;
        W[O_SL + t] = (t < total) ? s_sl[t] : 0;
    }
}

// st = relu([se|te] @ W_st + b_st).  M=256,N=512,K=640. 16x32 tile, BK=16, grid(16,16).
__global__ __launch_bounds__(256) void k_fc1(const float* __restrict__ se, const float* __restrict__ te,
                                             const float* __restrict__ B, const float* __restrict__ bias,
                                             float* __restrict__ C) {
    __shared__ float sA[16][17];
    __shared__ float sB[16][34];
    int tid = threadIdx.x;
    int c0 = blockIdx.x * 32, r0 = blockIdx.y * 16;
    int ar = tid >> 4, ak = tid & 15;        // A loader: 1 elem
    int bc = tid & 31, bk = tid >> 5;        // B loader: rows bk, bk+8
    int m = tid >> 4, n0 = (tid & 15) * 2;   // compute
    float acc0 = 0.f, acc1 = 0.f;

    float ra = se[(r0 + ar) * STD + ak];
    float rb0 = B[bk * 512 + c0 + bc];
    float rb1 = B[(bk + 8) * 512 + c0 + bc];
    sA[ak][ar] = ra; sB[bk][bc] = rb0; sB[bk + 8][bc] = rb1;
    __syncthreads();

    for (int kc = 16; kc < 640; kc += 16) {
        float na = (kc < 512) ? se[(r0 + ar) * STD + kc + ak]
                              : te[(r0 + ar) * TACD + kc - 512 + ak];
        float nb0 = B[(kc + bk) * 512 + c0 + bc];
        float nb1 = B[(kc + bk + 8) * 512 + c0 + bc];
        #pragma unroll
        for (int k = 0; k < 16; k++) {
            float a = sA[k][m];
            float2 b2 = *(const float2*)&sB[k][n0];
            acc0 += a * b2.x; acc1 += a * b2.y;
        }
        __syncthreads();
        sA[ak][ar] = na; sB[bk][bc] = nb0; sB[bk + 8][bc] = nb1;
        __syncthreads();
    }
    #pragma unroll
    for (int k = 0; k < 16; k++) {
        float a = sA[k][m];
        float2 b2 = *(const float2*)&sB[k][n0];
        acc0 += a * b2.x; acc1 += a * b2.y;
    }
    float2 bb = *(const float2*)&bias[c0 + n0];
    float2 v; v.x = fmaxf(acc0 + bb.x, 0.f); v.y = fmaxf(acc1 + bb.y, 0.f);
    *(float2*)&C[(r0 + m) * 512 + c0 + n0] = v;
}

// LNG = st @ W_q + b_q.  M=256,N=2056,K=512. 32x64 tile, 2x4 micro, BK=16, grid(33,8).
__global__ __launch_bounds__(256) void k_fc2(const float* __restrict__ A, const float* __restrict__ B,
                                             const float* __restrict__ bias, float* __restrict__ C) {
    __shared__ float sA[16][33];
    __shared__ float sB[16][68];
    int tid = threadIdx.x;
    int c0 = blockIdx.x * 64, r0 = blockIdx.y * 32;
    int ar = tid >> 3, ak = (tid & 7) * 2;   // A loader: float2
    int bc = tid & 63, bk0 = (tid >> 6) * 4; // B loader: 4 rows
    int mg = tid >> 4, ng = tid & 15;        // compute: rows mg, mg+16; cols ng*4..+3
    bool bok = (c0 + bc) < 2056;
    float acc[2][4] = {};

    float2 ra = *(const float2*)&A[(r0 + ar) * 512 + ak];
    float rb[4];
    #pragma unroll
    for (int j = 0; j < 4; j++) rb[j] = bok ? B[(bk0 + j) * 2056 + c0 + bc] : 0.f;
    sA[ak][ar] = ra.x; sA[ak + 1][ar] = ra.y;
    #pragma unroll
    for (int j = 0; j < 4; j++) sB[bk0 + j][bc] = rb[j];
    __syncthreads();

    for (int kc = 16; kc < 512; kc += 16) {
        float2 na = *(const float2*)&A[(r0 + ar) * 512 + kc + ak];
        float nb[4];
        #pragma unroll
        for (int j = 0; j < 4; j++) nb[j] = bok ? B[(kc + bk0 + j) * 2056 + c0 + bc] : 0.f;
        #pragma unroll
        for (int k = 0; k < 16; k++) {
            float a0 = sA[k][mg], a1 = sA[k][mg + 16];
            float4 b4 = *(const float4*)&sB[k][ng * 4];
            acc[0][0] += a0 * b4.x; acc[0][1] += a0 * b4.y; acc[0][2] += a0 * b4.z; acc[0][3] += a0 * b4.w;
            acc[1][0] += a1 * b4.x; acc[1][1] += a1 * b4.y; acc[1][2] += a1 * b4.z; acc[1][3] += a1 * b4.w;
        }
        __syncthreads();
        sA[ak][ar] = na.x; sA[ak + 1][ar] = na.y;
        #pragma unroll
        for (int j = 0; j < 4; j++) sB[bk0 + j][bc] = nb[j];
        __syncthreads();
    }
    #pragma unroll
    for (int k = 0; k < 16; k++) {
        float a0 = sA[k][mg], a1 = sA[k][mg + 16];
        float4 b4 = *(const float4*)&sB[k][ng * 4];
        acc[0][0] += a0 * b4.x; acc[0][1] += a0 * b4.y; acc[0][2] += a0 * b4.z; acc[0][3] += a0 * b4.w;
        acc[1][0] += a1 * b4.x; acc[1][1] += a1 * b4.y; acc[1][2] += a1 * b4.z; acc[1][3] += a1 * b4.w;
    }
    int c = c0 + ng * 4;
    if (c < 2056) {
        float4 bb = *(const float4*)&bias[c];
        #pragma unroll
        for (int i = 0; i < 2; i++) {
            float4 v;
            v.x = acc[i][0] + bb.x; v.y = acc[i][1] + bb.y;
            v.z = acc[i][2] + bb.z; v.w = acc[i][3] + bb.w;
            *(float4*)&C[(r0 + mg + 16 * i) * 2056 + c] = v;
        }
    }
}

// Per active arg t: split LNG row -> GQB(bf16) / none-logit (written straight to d_out);
// qk[t]=W_key@q_local, qb[t]=b_key.q_local.  Rows t in [total, 2048) get zero GQB (MFMA padding).
__global__ __launch_bounds__(256) void k_extract(const int* __restrict__ W, const float* __restrict__ LNG,
                                                 const float* __restrict__ Wkey, const float* __restrict__ bkey,
                                                 ushort* __restrict__ GQB, float* __restrict__ out, int L,
                                                 float* __restrict__ QK, float* __restrict__ QB) {
    int t = blockIdx.x;
    int total = W[O_TOT];
    int tid = threadIdx.x;
    if (t >= total) {
        if (tid >= 128) GQB[t * 128 + tid - 128] = 0;
        return;
    }
    int b = W[O_AB + t], slot = W[O_SL + t];
    const float* base = LNG + b * LNGW + slot * DIMQ;
    __shared__ float sl[CTXD];
    if (tid < 128) {
        sl[tid] = base[tid];
    } else {
        int d = tid - 128;
        GQB[t * 128 + d] = f2bf(base[129 + d]);
    }
    if (tid == 0) {
        int np = W[O_NP];
        out[np + t] = (float)t;
        out[L + np + t] = base[128];
    }
    __syncthreads();
    float acc = 0.f;
    const float* wr = Wkey + tid * 128;
    #pragma unroll
    for (int k = 0; k < 128; k += 4) {
        float4 w4 = *(const float4*)(wr + k);
        acc += w4.x * sl[k] + w4.y * sl[k + 1] + w4.z * sl[k + 2] + w4.w * sl[k + 3];
    }
    QK[t * 256 + tid] = acc;
    if (tid == 0) {
        float qb = 0.f;
        for (int k = 0; k < 128; k++) qb += bkey[k] * sl[k];
        QB[t] = qb;
    }
}

// gather + L2-normalize definition embeddings -> bf16 table in ws
__global__ __launch_bounds__(256) void k_gk(const int* __restrict__ gctx, const float* __restrict__ emb,
                                            ushort* __restrict__ gkb) {
    int tid = threadIdx.x;
    int g = blockIdx.x * 8 + (tid >> 5);
    int row = gctx[g];
    int c = tid & 31;
    float4 e = *(const float4*)(emb + (size_t)row * 128 + c * 4);
    float ss = e.x * e.x + e.y * e.y + e.z * e.z + e.w * e.w;
    #pragma unroll
    for (int off = 1; off < 32; off <<= 1) ss += __shfl_xor(ss, off);
    float sc = 1.f / (1e-7f + sqrtf(ss));
    ushort4 o;
    o.x = f2bf(e.x * sc); o.y = f2bf(e.y * sc); o.z = f2bf(e.z * sc); o.w = f2bf(e.w * sc);
    *(ushort4*)(gkb + (size_t)g * 128 + c * 4) = o;
}

// local logits: 4-lane groups, 16 rows/wave, QK staged in LDS (broadcast reads).
__global__ __launch_bounds__(256) void k_pairs(const int* __restrict__ W, const float* __restrict__ ctxv,
                                               const float* __restrict__ QK, const float* __restrict__ QB,
                                               float* __restrict__ out, int L) {
    int b = blockIdx.x >> 2, sub = blockIdx.x & 3;
    int as = W[O_AS + b];
    int cnt = W[O_AS + b + 1] - as;
    if (cnt == 0) return;
    int cs = W[O_CS + b];
    int len = W[O_CS + b + 1] - cs;
    int j0 = (len * sub) >> 2, j1 = (len * (sub + 1)) >> 2;
    __shared__ float sqk[MAXA][256];
    __shared__ float sqb[MAXA];
    __shared__ int sps[MAXA];
    int tid = threadIdx.x;
    for (int i = tid; i < cnt * 256; i += 256) sqk[i >> 8][i & 255] = QK[(as + (i >> 8)) * 256 + (i & 255)];
    if (tid < cnt) { sqb[tid] = QB[as + tid]; sps[tid] = W[O_PS + as + tid]; }
    __syncthreads();
    int wv = tid >> 6, lane = tid & 63;
    int g = lane >> 2, il = lane & 3;
    for (int jb = j0 + wv * 16; jb < j1; jb += 64) {
        int j = jb + g;
        bool ok = (j < j1);
        int row = cs + (ok ? j : j1 - 1);
        const float* xr = ctxv + (size_t)row * 256;
        float acc[MAXA] = {};
        #pragma unroll
        for (int c = 0; c < 16; c++) {
            float4 x4 = *(const float4*)(xr + c * 16 + il * 4);
            #pragma unroll
            for (int a = 0; a < MAXA; a++) {
                if (a < cnt) {
                    float4 q4 = *(const float4*)(&sqk[a][c * 16 + il * 4]);
                    acc[a] += x4.x * q4.x + x4.y * q4.y + x4.z * q4.z + x4.w * q4.w;
                }
            }
        }
        #pragma unroll
        for (int a = 0; a < MAXA; a++) {
            if (a < cnt) {
                float p = acc[a];
                p += __shfl_xor(p, 1);
                p += __shfl_xor(p, 2);
                if (il == 0 && ok) {
                    out[sps[a] + j] = (float)(as + a);
                    out[L + sps[a] + j] = p + sqb[a];
                }
            }
        }
    }
}

// global logits via bf16 MFMA. Block = 256 defs x 256 args.
// KEY CHANGE (R10): GKB A-fragments loaded ONCE per block into registers, reused across
// 8 arg-chunks (kills the L3-latency-bound GKB re-reads diagnosed R6-R9: writes evict
// the 5.1MB GKB from 4MB per-XCD L2, and ~4 outstanding 16B loads/wave can't cover
// ~1400cyc L3 latency). GQB (512KB, L2-resident) is the only re-read, prefetched
// one chunk ahead. Store phase: LDS-staged 1KB-contiguous per instruction (R9).
__global__ __launch_bounds__(256) void k_gglob(const int* __restrict__ W, const ushort* __restrict__ GQB,
                                               const ushort* __restrict__ GKB, float* __restrict__ out, int L) {
    __shared__ float tile[32][264];   // 33.8KB; stride 264 -> ds_write ~4-way, acceptable
    int total = W[O_TOT], np = W[O_NP];
    int t0 = blockIdx.y * 256;
    if (t0 >= total) return;
    float* outi = out + np + total;
    float* outv = out + L + np + total;
    int g0 = blockIdx.x * 256;
    int tid = threadIdx.x, wv = tid >> 6, lane = tid & 63;
    int lhi = lane >> 4, llo = lane & 15;
    int gw = wv * 64;   // wave's 64-def sub-range within block
    // A fragments (defs, from GKB): loaded ONCE, reused for all arg-chunks
    bf16x8 afr[4][4];
    #pragma unroll
    for (int nt = 0; nt < 4; nt++) {
        int g = g0 + gw + nt * 16 + llo;
        const ushort* ap = GKB + (size_t)(g < DEFN ? g : DEFN - 1) * 128 + lhi * 8;
        #pragma unroll
        for (int kk = 0; kk < 4; kk++)
            afr[nt][kk] = *(const bf16x8*)(ap + kk * 32);
    }
    int nchunk = (total - t0 + 31) >> 5;
    if (nchunk > 8) nchunk = 8;
    // prologue: load B-frags for chunk 0
    bf16x8 bfr[2][4];
    #pragma unroll
    for (int ts = 0; ts < 2; ts++)
        #pragma unroll
        for (int kk = 0; kk < 4; kk++)
            bfr[ts][kk] = *(const bf16x8*)(GQB + (size_t)(t0 + ts * 16 + llo) * 128 + kk * 32 + lhi * 8);
    for (int tc = 0; tc < nchunk; tc++) {
        int t1 = t0 + tc * 32;
        f32x4 acc[2][4] = {};
        #pragma unroll
        for (int nt = 0; nt < 4; nt++)
            #pragma unroll
            for (int kk = 0; kk < 4; kk++)
                #pragma unroll
                for (int ts = 0; ts < 2; ts++)
                    acc[ts][nt] = __builtin_amdgcn_mfma_f32_16x16x32_bf16(afr[nt][kk], bfr[ts][kk], acc[ts][nt], 0, 0, 0);
        // prefetch next chunk's B-frags (overlaps LDS staging + stores)
        if (tc + 1 < nchunk) {
            int t2 = t1 + 32;
            #pragma unroll
            for (int ts = 0; ts < 2; ts++)
                #pragma unroll
                for (int kk = 0; kk < 4; kk++)
                    bfr[ts][kk] = *(const bf16x8*)(GQB + (size_t)(t2 + ts * 16 + llo) * 128 + kk * 32 + lhi * 8);
        }
        // D layout: col(=arg)=llo, row(=def)=lhi*4+reg  -> LDS
        #pragma unroll
        for (int ts = 0; ts < 2; ts++)
            *(f32x4*)&tile[ts * 16 + llo][gw + (0) * 16 + lhi * 4] = acc[ts][0];
        #pragma unroll
        for (int nt = 1; nt < 4; nt++)
            #pragma unroll
            for (int ts = 0; ts < 2; ts++)
                *(f32x4*)&tile[ts * 16 + llo][gw + nt * 16 + lhi * 4] = acc[ts][nt];
        __syncthreads();
        // store phase: wave wv streams rows wv*8..wv*8+7; 1KB contiguous per instruction
        int c = lane * 4;
        bool gok = (g0 + c) < DEFN;
        #pragma unroll
        for (int r8 = 0; r8 < 8; r8++) {
            int r = wv * 8 + r8;
            int t = t1 + r;
            if (t >= total) break;
            if (gok) {
                size_t rb = (size_t)t * DEFN + g0;
                float ft = (float)t;
                f32x4 fi = {ft, ft, ft, ft};
                *(f32x4*)(outv + rb + c) = *(const f32x4*)&tile[r][c];
                *(f32x4*)(outi + rb + c) = fi;
            }
        }
        __syncthreads();
    }
}

extern "C" void kernel_launch(void* const* d_in, const int* in_sizes, int n_in,
                              void* d_out, int out_size, void* d_ws, size_t ws_size,
                              hipStream_t stream) {
    const float* ctx_vals  = (const float*)d_in[0];
    const float* state_emb = (const float*)d_in[1];
    const float* tactic    = (const float*)d_in[2];
    const float* emb       = (const float*)d_in[3];
    const float* W_key     = (const float*)d_in[4];
    const float* b_key     = (const float*)d_in[5];
    const float* W_st      = (const float*)d_in[6];
    const float* b_st      = (const float*)d_in[7];
    const float* W_q       = (const float*)d_in[8];
    const float* b_q       = (const float*)d_in[9];
    const int* ctx_ids     = (const int*)d_in[10];
    const int* arg_cnt     = (const int*)d_in[11];
    const int* gctx        = (const int*)d_in[12];
    int n_ctx = in_sizes[10];
    int L = out_size / 2;
    int* W  = (int*)d_ws;
    float* F = (float*)d_ws;
    float* out = (float*)d_out;

    k_bounds<<<dim3((n_ctx + 255) / 256), dim3(256), 0, stream>>>(ctx_ids, n_ctx, W);
    k_scan<<<dim3(1), dim3(256), 0, stream>>>(arg_cnt, W);
    k_fc1<<<dim3(16, 16), dim3(256), 0, stream>>>(state_emb, tactic, W_st, b_st, F + F_ST);
    k_fc2<<<dim3(33, 8), dim3(256), 0, stream>>>(F + F_ST, W_q, b_q, F + F_LNG);
    k_extract<<<dim3(2048), dim3(256), 0, stream>>>(W, F + F_LNG, W_key, b_key,
                                                    (ushort*)(F + F_GQ), out, L, F + F_QK, F + F_QB);
    k_pairs<<<dim3(1024), dim3(256), 0, stream>>>(W, ctx_vals, F + F_QK, F + F_QB, out, L);
    k_gk<<<dim3(2500), dim3(256), 0, stream>>>(gctx, emb, (ushort*)(F + F_GKB));
    k_gglob<<<dim3(79, 8), dim3(256), 0, stream>>>(W, (ushort*)(F + F_GQ), (ushort*)(F + F_GKB), out, L);
}

// Round 11
// 164.711 us; speedup vs baseline: 1.1470x; 1.0942x over previous
//
#include <hip/hip_runtime.h>

#define BSZ 256
#define MAXA 8
#define CTXD 128
#define HID 512
#define STD 512
#define TACD 128
#define DEFN 20000
#define CVD 256
#define DIMQ 257
#define LNGW 2056   // MAX_ARGS*DIMQ

typedef __attribute__((ext_vector_type(8))) short bf16x8;
typedef __attribute__((ext_vector_type(4))) float f32x4;

// ---- ws layout ----
// int region
#define O_TOT 0
#define O_NP  1
#define O_CS  16      // ctx_start[257]
#define O_AS  288     // arg_start[257]
#define O_AB  560     // arg_batch[2048]
#define O_SL  2608    // arg_slot[2048]
#define O_PS  4656    // pair_start[2049]
// float region (offsets in floats)
#define F_GQ   8192     // GQB bf16 2048*128 (occupies 65536 float-slots; padded rows zeroed)
#define F_QB   272384    // 2048                -> 274432
#define F_ST   438272    // 256*512             -> 569344
#define F_LNG  569344    // 256*2056            -> 1095680
#define F_QK   1095680   // 2048*256            -> 1619968 floats = 6.48MB
#define F_GKB  274432    // bf16 gk: 20000*128*2B -> float-slots 274432..1585152 (overlays dead ST/LNG/QK)

__device__ __forceinline__ ushort f2bf(float f) {
    uint u = __float_as_uint(f);
    return (ushort)((u + 0x7FFFu + ((u >> 16) & 1u)) >> 16);
}

// parallel lower_bound table: for each b in [0,256], W[O_CS+b] = first i with ctx_ids[i] >= b
__global__ __launch_bounds__(256) void k_bounds(const int* __restrict__ ctx_ids, int n_ctx,
                                                int* __restrict__ W) {
    int i = blockIdx.x * 256 + threadIdx.x;
    if (i >= n_ctx) return;
    int cur = ctx_ids[i];
    int prev = (i == 0) ? -1 : ctx_ids[i - 1];
    for (int b = prev + 1; b <= cur; b++) W[O_CS + b] = i;
    if (i == n_ctx - 1) {
        for (int b = cur + 1; b <= BSZ; b++) W[O_CS + b] = n_ctx;
    }
}

// small scans over 256 entries (reads ctx starts from W)
__global__ __launch_bounds__(256) void k_scan(const int* __restrict__ arg_cnt, int* __restrict__ W) {
    __shared__ int s_start[BSZ + 1];
    __shared__ int s_len[BSZ];
    __shared__ int s_scan[BSZ];
    __shared__ int s_as[BSZ + 1];
    __shared__ int s_ab[2048];
    __shared__ int s_sl[2048];
    __shared__ int s_ps[BSZ];
    int tid = threadIdx.x;
    s_start[tid] = W[O_CS + tid];
    if (tid == 0) s_start[BSZ] = W[O_CS + BSZ];
    int c = arg_cnt[tid];
    s_scan[tid] = c;
    __syncthreads();
    s_len[tid] = s_start[tid + 1] - s_start[tid];
    for (int off = 1; off < BSZ; off <<= 1) {
        int v = s_scan[tid];
        int a = (tid >= off) ? s_scan[tid - off] : 0;
        __syncthreads();
        s_scan[tid] = v + a;
        __syncthreads();
    }
    int astart = s_scan[tid] - c;
    s_as[tid] = astart;
    if (tid == BSZ - 1) s_as[BSZ] = s_scan[tid];
    __syncthreads();
    int total = s_as[BSZ];
    for (int k = 0; k < c; k++) { s_ab[astart + k] = tid; s_sl[astart + k] = k; }
    __syncthreads();
    int base = tid * 8;
    int loc[8]; int run = 0;
    for (int j = 0; j < 8; j++) {
        int t = base + j;
        int l = (t < total) ? s_len[s_ab[t]] : 0;
        loc[j] = run; run += l;
    }
    s_ps[tid] = run;
    __syncthreads();
    for (int off = 1; off < BSZ; off <<= 1) {
        int v = s_ps[tid];
        int a = (tid >= off) ? s_ps[tid - off] : 0;
        __syncthreads();
        s_ps[tid] = v + a;
        __syncthreads();
    }
    int pbase = s_ps[tid] - run;
    int np = s_ps[BSZ - 1];
    W[O_AS + tid] = astart;
    if (tid == 0) { W[O_AS + BSZ] = total; W[O_TOT] = total; W[O_NP] = np; W[O_PS + 2048] = np; }
    for (int j = 0; j < 8; j++) {
        int t = base + j;
        W[O_PS + t] = pbase + loc[j];
        W[O_AB + t] = (t < total) ? s_ab[t] : 0;
        W[O_SL + t] = (t < total) ? s_sl[t] : 0;
    }
}

// st = relu([se|te] @ W_st + b_st).  M=256,N=512,K=640. 16x32 tile, grid(16,16).
// R11: 1024 threads = 4 K-groups of 256; each group covers K/4=160 (10 iters of BK=16).
// 4x memory-level parallelism per CU, 4x fewer serialized latency exposures.
__global__ __launch_bounds__(1024) void k_fc1(const float* __restrict__ se, const float* __restrict__ te,
                                              const float* __restrict__ B, const float* __restrict__ bias,
                                              float* __restrict__ C) {
    __shared__ float sA[4][16][17];
    __shared__ float sB[4][16][34];
    __shared__ float red[4][16][32];
    int tid = threadIdx.x;
    int kg = tid >> 8, g = tid & 255;
    int c0 = blockIdx.x * 32, r0 = blockIdx.y * 16;
    int ar = g >> 4, ak = g & 15;        // A loader
    int bc = g & 31, bk = g >> 5;        // B loader: rows bk, bk+8
    int m = g >> 4, n0 = (g & 15) * 2;   // compute
    int kbase = kg * 160;
    float acc0 = 0.f, acc1 = 0.f;

    int k0 = kbase + ak;
    float ra = (k0 < 512) ? se[(r0 + ar) * STD + k0] : te[(r0 + ar) * TACD + k0 - 512];
    float rb0 = B[(kbase + bk) * 512 + c0 + bc];
    float rb1 = B[(kbase + bk + 8) * 512 + c0 + bc];
    sA[kg][ak][ar] = ra; sB[kg][bk][bc] = rb0; sB[kg][bk + 8][bc] = rb1;
    __syncthreads();

    for (int kc = kbase + 16; kc < kbase + 160; kc += 16) {
        int k = kc + ak;
        float na = (k < 512) ? se[(r0 + ar) * STD + k] : te[(r0 + ar) * TACD + k - 512];
        float nb0 = B[(kc + bk) * 512 + c0 + bc];
        float nb1 = B[(kc + bk + 8) * 512 + c0 + bc];
        #pragma unroll
        for (int k2 = 0; k2 < 16; k2++) {
            float a = sA[kg][k2][m];
            float2 b2 = *(const float2*)&sB[kg][k2][n0];
            acc0 += a * b2.x; acc1 += a * b2.y;
        }
        __syncthreads();
        sA[kg][ak][ar] = na; sB[kg][bk][bc] = nb0; sB[kg][bk + 8][bc] = nb1;
        __syncthreads();
    }
    #pragma unroll
    for (int k2 = 0; k2 < 16; k2++) {
        float a = sA[kg][k2][m];
        float2 b2 = *(const float2*)&sB[kg][k2][n0];
        acc0 += a * b2.x; acc1 += a * b2.y;
    }
    red[kg][m][n0] = acc0; red[kg][m][n0 + 1] = acc1;
    __syncthreads();
    if (kg == 0) {
        acc0 += red[1][m][n0] + red[2][m][n0] + red[3][m][n0];
        acc1 += red[1][m][n0 + 1] + red[2][m][n0 + 1] + red[3][m][n0 + 1];
        float2 bb = *(const float2*)&bias[c0 + n0];
        float2 v; v.x = fmaxf(acc0 + bb.x, 0.f); v.y = fmaxf(acc1 + bb.y, 0.f);
        *(float2*)&C[(r0 + m) * 512 + c0 + n0] = v;
    }
}

// LNG = st @ W_q + b_q.  M=256,N=2056,K=512. 32x64 tile, grid(33,8).
// R11: 1024 threads = 4 K-groups of 256; each covers K/4=128 (8 iters of BK=16).
__global__ __launch_bounds__(1024) void k_fc2(const float* __restrict__ A, const float* __restrict__ B,
                                              const float* __restrict__ bias, float* __restrict__ C) {
    __shared__ float sA[4][16][33];
    __shared__ float sB[4][16][68];
    __shared__ float red[4][32][68];
    int tid = threadIdx.x;
    int kg = tid >> 8, g = tid & 255;
    int c0 = blockIdx.x * 64, r0 = blockIdx.y * 32;
    int ar = g >> 3, ak = (g & 7) * 2;   // A loader: float2
    int bc = g & 63, bk0 = (g >> 6) * 4; // B loader: 4 rows
    int mg = g >> 4, ng = g & 15;        // compute
    bool bok = (c0 + bc) < 2056;
    int kbase = kg * 128;
    float acc[2][4] = {};

    float2 ra = *(const float2*)&A[(r0 + ar) * 512 + kbase + ak];
    float rb[4];
    #pragma unroll
    for (int j = 0; j < 4; j++) rb[j] = bok ? B[(kbase + bk0 + j) * 2056 + c0 + bc] : 0.f;
    sA[kg][ak][ar] = ra.x; sA[kg][ak + 1][ar] = ra.y;
    #pragma unroll
    for (int j = 0; j < 4; j++) sB[kg][bk0 + j][bc] = rb[j];
    __syncthreads();

    for (int kc = kbase + 16; kc < kbase + 128; kc += 16) {
        float2 na = *(const float2*)&A[(r0 + ar) * 512 + kc + ak];
        float nb[4];
        #pragma unroll
        for (int j = 0; j < 4; j++) nb[j] = bok ? B[(kc + bk0 + j) * 2056 + c0 + bc] : 0.f;
        #pragma unroll
        for (int k = 0; k < 16; k++) {
            float a0 = sA[kg][k][mg], a1 = sA[kg][k][mg + 16];
            float4 b4 = *(const float4*)&sB[kg][k][ng * 4];
            acc[0][0] += a0 * b4.x; acc[0][1] += a0 * b4.y; acc[0][2] += a0 * b4.z; acc[0][3] += a0 * b4.w;
            acc[1][0] += a1 * b4.x; acc[1][1] += a1 * b4.y; acc[1][2] += a1 * b4.z; acc[1][3] += a1 * b4.w;
        }
        __syncthreads();
        sA[kg][ak][ar] = na.x; sA[kg][ak + 1][ar] = na.y;
        #pragma unroll
        for (int j = 0; j < 4; j++) sB[kg][bk0 + j][bc] = nb[j];
        __syncthreads();
    }
    #pragma unroll
    for (int k = 0; k < 16; k++) {
        float a0 = sA[kg][k][mg], a1 = sA[kg][k][mg + 16];
        float4 b4 = *(const float4*)&sB[kg][k][ng * 4];
        acc[0][0] += a0 * b4.x; acc[0][1] += a0 * b4.y; acc[0][2] += a0 * b4.z; acc[0][3] += a0 * b4.w;
        acc[1][0] += a1 * b4.x; acc[1][1] += a1 * b4.y; acc[1][2] += a1 * b4.z; acc[1][3] += a1 * b4.w;
    }
    #pragma unroll
    for (int i = 0; i < 2; i++)
        #pragma unroll
        for (int j = 0; j < 4; j++)
            red[kg][mg + 16 * i][ng * 4 + j] = acc[i][j];
    __syncthreads();
    if (kg == 0) {
        int c = c0 + ng * 4;
        if (c < 2056) {
            float4 bb = *(const float4*)&bias[c];
            #pragma unroll
            for (int i = 0; i < 2; i++) {
                int r = mg + 16 * i;
                float4 v;
                v.x = acc[i][0] + red[1][r][ng * 4 + 0] + red[2][r][ng * 4 + 0] + red[3][r][ng * 4 + 0] + bb.x;
                v.y = acc[i][1] + red[1][r][ng * 4 + 1] + red[2][r][ng * 4 + 1] + red[3][r][ng * 4 + 1] + bb.y;
                v.z = acc[i][2] + red[1][r][ng * 4 + 2] + red[2][r][ng * 4 + 2] + red[3][r][ng * 4 + 2] + bb.z;
                v.w = acc[i][3] + red[1][r][ng * 4 + 3] + red[2][r][ng * 4 + 3] + red[3][r][ng * 4 + 3] + bb.w;
                *(float4*)&C[(r0 + r) * 2056 + c] = v;
            }
        }
    }
}

// Per active arg t: split LNG row -> GQB(bf16) / none-logit (written straight to d_out);
// qk[t]=W_key@q_local, qb[t]=b_key.q_local.  Rows t in [total, 2048) get zero GQB (MFMA padding).
__global__ __launch_bounds__(256) void k_extract(const int* __restrict__ W, const float* __restrict__ LNG,
                                                 const float* __restrict__ Wkey, const float* __restrict__ bkey,
                                                 ushort* __restrict__ GQB, float* __restrict__ out, int L,
                                                 float* __restrict__ QK, float* __restrict__ QB) {
    int t = blockIdx.x;
    int total = W[O_TOT];
    int tid = threadIdx.x;
    if (t >= total) {
        if (tid >= 128) GQB[t * 128 + tid - 128] = 0;
        return;
    }
    int b = W[O_AB + t], slot = W[O_SL + t];
    const float* base = LNG + b * LNGW + slot * DIMQ;
    __shared__ float sl[CTXD];
    if (tid < 128) {
        sl[tid] = base[tid];
    } else {
        int d = tid - 128;
        GQB[t * 128 + d] = f2bf(base[129 + d]);
    }
    if (tid == 0) {
        int np = W[O_NP];
        out[np + t] = (float)t;
        out[L + np + t] = base[128];
    }
    __syncthreads();
    float acc = 0.f;
    const float* wr = Wkey + tid * 128;
    #pragma unroll
    for (int k = 0; k < 128; k += 4) {
        float4 w4 = *(const float4*)(wr + k);
        acc += w4.x * sl[k] + w4.y * sl[k + 1] + w4.z * sl[k + 2] + w4.w * sl[k + 3];
    }
    QK[t * 256 + tid] = acc;
    if (tid == 0) {
        float qb = 0.f;
        for (int k = 0; k < 128; k++) qb += bkey[k] * sl[k];
        QB[t] = qb;
    }
}

// gather + L2-normalize definition embeddings -> bf16 table in ws
__global__ __launch_bounds__(256) void k_gk(const int* __restrict__ gctx, const float* __restrict__ emb,
                                            ushort* __restrict__ gkb) {
    int tid = threadIdx.x;
    int g = blockIdx.x * 8 + (tid >> 5);
    int row = gctx[g];
    int c = tid & 31;
    float4 e = *(const float4*)(emb + (size_t)row * 128 + c * 4);
    float ss = e.x * e.x + e.y * e.y + e.z * e.z + e.w * e.w;
    #pragma unroll
    for (int off = 1; off < 32; off <<= 1) ss += __shfl_xor(ss, off);
    float sc = 1.f / (1e-7f + sqrtf(ss));
    ushort4 o;
    o.x = f2bf(e.x * sc); o.y = f2bf(e.y * sc); o.z = f2bf(e.z * sc); o.w = f2bf(e.w * sc);
    *(ushort4*)(gkb + (size_t)g * 128 + c * 4) = o;
}

// local logits: 4-lane groups, 16 rows/wave, QK staged in LDS (broadcast reads).
__global__ __launch_bounds__(256) void k_pairs(const int* __restrict__ W, const float* __restrict__ ctxv,
                                               const float* __restrict__ QK, const float* __restrict__ QB,
                                               float* __restrict__ out, int L) {
    int b = blockIdx.x >> 2, sub = blockIdx.x & 3;
    int as = W[O_AS + b];
    int cnt = W[O_AS + b + 1] - as;
    if (cnt == 0) return;
    int cs = W[O_CS + b];
    int len = W[O_CS + b + 1] - cs;
    int j0 = (len * sub) >> 2, j1 = (len * (sub + 1)) >> 2;
    __shared__ float sqk[MAXA][256];
    __shared__ float sqb[MAXA];
    __shared__ int sps[MAXA];
    int tid = threadIdx.x;
    for (int i = tid; i < cnt * 256; i += 256) sqk[i >> 8][i & 255] = QK[(as + (i >> 8)) * 256 + (i & 255)];
    if (tid < cnt) { sqb[tid] = QB[as + tid]; sps[tid] = W[O_PS + as + tid]; }
    __syncthreads();
    int wv = tid >> 6, lane = tid & 63;
    int g = lane >> 2, il = lane & 3;
    for (int jb = j0 + wv * 16; jb < j1; jb += 64) {
        int j = jb + g;
        bool ok = (j < j1);
        int row = cs + (ok ? j : j1 - 1);
        const float* xr = ctxv + (size_t)row * 256;
        float acc[MAXA] = {};
        #pragma unroll
        for (int c = 0; c < 16; c++) {
            float4 x4 = *(const float4*)(xr + c * 16 + il * 4);
            #pragma unroll
            for (int a = 0; a < MAXA; a++) {
                if (a < cnt) {
                    float4 q4 = *(const float4*)(&sqk[a][c * 16 + il * 4]);
                    acc[a] += x4.x * q4.x + x4.y * q4.y + x4.z * q4.z + x4.w * q4.w;
                }
            }
        }
        #pragma unroll
        for (int a = 0; a < MAXA; a++) {
            if (a < cnt) {
                float p = acc[a];
                p += __shfl_xor(p, 1);
                p += __shfl_xor(p, 2);
                if (il == 0 && ok) {
                    out[sps[a] + j] = (float)(as + a);
                    out[L + sps[a] + j] = p + sqb[a];
                }
            }
        }
    }
}

// global logits via bf16 MFMA. Block = 256 defs x 256 args. GKB A-frags register-resident
// (loaded once per block); GQB B-frags prefetched one 32-arg chunk ahead; LDS-staged
// 1KB-contiguous stores for value+index planes.
__global__ __launch_bounds__(256) void k_gglob(const int* __restrict__ W, const ushort* __restrict__ GQB,
                                               const ushort* __restrict__ GKB, float* __restrict__ out, int L) {
    __shared__ float tile[32][264];
    int total = W[O_TOT], np = W[O_NP];
    int t0 = blockIdx.y * 256;
    if (t0 >= total) return;
    float* outi = out + np + total;
    float* outv = out + L + np + total;
    int g0 = blockIdx.x * 256;
    int tid = threadIdx.x, wv = tid >> 6, lane = tid & 63;
    int lhi = lane >> 4, llo = lane & 15;
    int gw = wv * 64;
    bf16x8 afr[4][4];
    #pragma unroll
    for (int nt = 0; nt < 4; nt++) {
        int g = g0 + gw + nt * 16 + llo;
        const ushort* ap = GKB + (size_t)(g < DEFN ? g : DEFN - 1) * 128 + lhi * 8;
        #pragma unroll
        for (int kk = 0; kk < 4; kk++)
            afr[nt][kk] = *(const bf16x8*)(ap + kk * 32);
    }
    int nchunk = (total - t0 + 31) >> 5;
    if (nchunk > 8) nchunk = 8;
    bf16x8 bfr[2][4];
    #pragma unroll
    for (int ts = 0; ts < 2; ts++)
        #pragma unroll
        for (int kk = 0; kk < 4; kk++)
            bfr[ts][kk] = *(const bf16x8*)(GQB + (size_t)(t0 + ts * 16 + llo) * 128 + kk * 32 + lhi * 8);
    for (int tc = 0; tc < nchunk; tc++) {
        int t1 = t0 + tc * 32;
        f32x4 acc[2][4] = {};
        #pragma unroll
        for (int nt = 0; nt < 4; nt++)
            #pragma unroll
            for (int kk = 0; kk < 4; kk++)
                #pragma unroll
                for (int ts = 0; ts < 2; ts++)
                    acc[ts][nt] = __builtin_amdgcn_mfma_f32_16x16x32_bf16(afr[nt][kk], bfr[ts][kk], acc[ts][nt], 0, 0, 0);
        if (tc + 1 < nchunk) {
            int t2 = t1 + 32;
            #pragma unroll
            for (int ts = 0; ts < 2; ts++)
                #pragma unroll
                for (int kk = 0; kk < 4; kk++)
                    bfr[ts][kk] = *(const bf16x8*)(GQB + (size_t)(t2 + ts * 16 + llo) * 128 + kk * 32 + lhi * 8);
        }
        #pragma unroll
        for (int nt = 0; nt < 4; nt++)
            #pragma unroll
            for (int ts = 0; ts < 2; ts++)
                *(f32x4*)&tile[ts * 16 + llo][gw + nt * 16 + lhi * 4] = acc[ts][nt];
        __syncthreads();
        int c = lane * 4;
        bool gok = (g0 + c) < DEFN;
        #pragma unroll
        for (int r8 = 0; r8 < 8; r8++) {
            int r = wv * 8 + r8;
            int t = t1 + r;
            if (t >= total) break;
            if (gok) {
                size_t rb = (size_t)t * DEFN + g0;
                float ft = (float)t;
                f32x4 fi = {ft, ft, ft, ft};
                *(f32x4*)(outv + rb + c) = *(const f32x4*)&tile[r][c];
                *(f32x4*)(outi + rb + c) = fi;
            }
        }
        __syncthreads();
    }
}

extern "C" void kernel_launch(void* const* d_in, const int* in_sizes, int n_in,
                              void* d_out, int out_size, void* d_ws, size_t ws_size,
                              hipStream_t stream) {
    const float* ctx_vals  = (const float*)d_in[0];
    const float* state_emb = (const float*)d_in[1];
    const float* tactic    = (const float*)d_in[2];
    const float* emb       = (const float*)d_in[3];
    const float* W_key     = (const float*)d_in[4];
    const float* b_key     = (const float*)d_in[5];
    const float* W_st      = (const float*)d_in[6];
    const float* b_st      = (const float*)d_in[7];
    const float* W_q       = (const float*)d_in[8];
    const float* b_q       = (const float*)d_in[9];
    const int* ctx_ids     = (const int*)d_in[10];
    const int* arg_cnt     = (const int*)d_in[11];
    const int* gctx        = (const int*)d_in[12];
    int n_ctx = in_sizes[10];
    int L = out_size / 2;
    int* W  = (int*)d_ws;
    float* F = (float*)d_ws;
    float* out = (float*)d_out;

    k_bounds<<<dim3((n_ctx + 255) / 256), dim3(256), 0, stream>>>(ctx_ids, n_ctx, W);
    k_scan<<<dim3(1), dim3(256), 0, stream>>>(arg_cnt, W);
    k_fc1<<<dim3(16, 16), dim3(1024), 0, stream>>>(state_emb, tactic, W_st, b_st, F + F_ST);
    k_fc2<<<dim3(33, 8), dim3(1024), 0, stream>>>(F + F_ST, W_q, b_q, F + F_LNG);
    k_extract<<<dim3(2048), dim3(256), 0, stream>>>(W, F + F_LNG, W_key, b_key,
                                                    (ushort*)(F + F_GQ), out, L, F + F_QK, F + F_QB);
    k_pairs<<<dim3(1024), dim3(256), 0, stream>>>(W, ctx_vals, F + F_QK, F + F_QB, out, L);
    k_gk<<<dim3(2500), dim3(256), 0, stream>>>(gctx, emb, (ushort*)(F + F_GKB));
    k_gglob<<<dim3(79, 8), dim3(256), 0, stream>>>(W, (ushort*)(F + F_GQ), (ushort*)(F + F_GKB), out, L);
}

// Round 12
// 152.911 us; speedup vs baseline: 1.2355x; 1.0772x over previous
//
#include <hip/hip_runtime.h>

#define BSZ 256
#define MAXA 8
#define CTXD 128
#define HID 512
#define STD 512
#define TACD 128
#define DEFN 20000
#define CVD 256
#define DIMQ 257
#define LNGW 2056   // MAX_ARGS*DIMQ

typedef __attribute__((ext_vector_type(8))) short bf16x8;
typedef __attribute__((ext_vector_type(4))) float f32x4;

// ---- ws layout ----
// int region
#define O_TOT 0
#define O_NP  1
#define O_CS  16      // ctx_start[257]
#define O_AS  288     // arg_start[257]
#define O_AB  560     // arg_batch[2048]
#define O_SL  2608    // arg_slot[2048]
#define O_PS  4656    // pair_start[2049]
// float region (offsets in floats).  Live intervals verified:
//  GQB/QB live extract->gglob/pairs (low, never overlapped)
//  WstT,stb dead after fc2; LNG dead after extract; WqT dead after fc2 -> QK overlays WqT
//  GKB (gk->gglob) overlays WstT/stb/LNG/WqT/QK (all dead by gk)
#define F_GQB  8192      // 2048*128 ushort = 131072 fl -> 139264
#define F_QB   139264    // 2048 -> 141312
#define F_WST  141312    // 512*640 ushort = 163840 fl -> 305152
#define F_STB  305152    // 256*512 ushort = 65536 fl -> 370688
#define F_LNG  370688    // 256*2056 fp32 = 526336 fl -> 897024
#define F_WQT  897024    // 2056*512 ushort = 526336 fl -> 1423360
#define F_QK   897024    // 2048*256 fp32 (overlays dead WqT)
#define F_GKB  141312    // 20000*128 ushort = 1280000 fl -> 1421312 (overlays dead fc buffers)
// max extent 1423360 fl = 5.69MB < proven 6.48MB ws

__device__ __forceinline__ ushort f2bf(float f) {
    uint u = __float_as_uint(f);
    return (ushort)((u + 0x7FFFu + ((u >> 16) & 1u)) >> 16);
}

// parallel lower_bound table: for each b in [0,256], W[O_CS+b] = first i with ctx_ids[i] >= b
__global__ __launch_bounds__(256) void k_bounds(const int* __restrict__ ctx_ids, int n_ctx,
                                                int* __restrict__ W) {
    int i = blockIdx.x * 256 + threadIdx.x;
    if (i >= n_ctx) return;
    int cur = ctx_ids[i];
    int prev = (i == 0) ? -1 : ctx_ids[i - 1];
    for (int b = prev + 1; b <= cur; b++) W[O_CS + b] = i;
    if (i == n_ctx - 1) {
        for (int b = cur + 1; b <= BSZ; b++) W[O_CS + b] = n_ctx;
    }
}

// small scans over 256 entries (reads ctx starts from W)
__global__ __launch_bounds__(256) void k_scan(const int* __restrict__ arg_cnt, int* __restrict__ W) {
    __shared__ int s_start[BSZ + 1];
    __shared__ int s_len[BSZ];
    __shared__ int s_scan[BSZ];
    __shared__ int s_as[BSZ + 1];
    __shared__ int s_ab[2048];
    __shared__ int s_sl[2048];
    __shared__ int s_ps[BSZ];
    int tid = threadIdx.x;
    s_start[tid] = W[O_CS + tid];
    if (tid == 0) s_start[BSZ] = W[O_CS + BSZ];
    int c = arg_cnt[tid];
    s_scan[tid] = c;
    __syncthreads();
    s_len[tid] = s_start[tid + 1] - s_start[tid];
    for (int off = 1; off < BSZ; off <<= 1) {
        int v = s_scan[tid];
        int a = (tid >= off) ? s_scan[tid - off] : 0;
        __syncthreads();
        s_scan[tid] = v + a;
        __syncthreads();
    }
    int astart = s_scan[tid] - c;
    s_as[tid] = astart;
    if (tid == BSZ - 1) s_as[BSZ] = s_scan[tid];
    __syncthreads();
    int total = s_as[BSZ];
    for (int k = 0; k < c; k++) { s_ab[astart + k] = tid; s_sl[astart + k] = k; }
    __syncthreads();
    int base = tid * 8;
    int loc[8]; int run = 0;
    for (int j = 0; j < 8; j++) {
        int t = base + j;
        int l = (t < total) ? s_len[s_ab[t]] : 0;
        loc[j] = run; run += l;
    }
    s_ps[tid] = run;
    __syncthreads();
    for (int off = 1; off < BSZ; off <<= 1) {
        int v = s_ps[tid];
        int a = (tid >= off) ? s_ps[tid - off] : 0;
        __syncthreads();
        s_ps[tid] = v + a;
        __syncthreads();
    }
    int pbase = s_ps[tid] - run;
    int np = s_ps[BSZ - 1];
    W[O_AS + tid] = astart;
    if (tid == 0) { W[O_AS + BSZ] = total; W[O_TOT] = total; W[O_NP] = np; W[O_PS + 2048] = np; }
    for (int j = 0; j < 8; j++) {
        int t = base + j;
        W[O_PS + t] = pbase + loc[j];
        W[O_AB + t] = (t < total) ? s_ab[t] : 0;
        W[O_SL + t] = (t < total) ? s_sl[t] : 0;
    }
}

// transpose fp32 [R][C] -> bf16 [C][R]
__global__ __launch_bounds__(256) void k_trans(const float* __restrict__ in, ushort* __restrict__ out,
                                               int R, int C) {
    __shared__ float t[32][33];
    int c0 = blockIdx.x * 32, r0 = blockIdx.y * 32;
    int lx = threadIdx.x & 31, ly = threadIdx.x >> 5;
    #pragma unroll
    for (int i = 0; i < 32; i += 8) {
        int r = r0 + ly + i, c = c0 + lx;
        t[ly + i][lx] = (r < R && c < C) ? in[(size_t)r * C + c] : 0.f;
    }
    __syncthreads();
    #pragma unroll
    for (int i = 0; i < 32; i += 8) {
        int oc = c0 + ly + i;   // output row (= original col)
        int orr = r0 + lx;      // output col (= original row)
        if (oc < C && orr < R) out[(size_t)oc * R + orr] = f2bf(t[lx][ly + i]);
    }
}

__device__ __forceinline__ bf16x8 cvt8(float4 a, float4 b) {
    bf16x8 r;
    r[0] = (short)f2bf(a.x); r[1] = (short)f2bf(a.y); r[2] = (short)f2bf(a.z); r[3] = (short)f2bf(a.w);
    r[4] = (short)f2bf(b.x); r[5] = (short)f2bf(b.y); r[6] = (short)f2bf(b.z); r[7] = (short)f2bf(b.w);
    return r;
}

// stb = bf16(relu([se|te] @ W_st + b_st)).  LDS-free MFMA, 1 wave/block, 16m x 32n tile.
// grid 256 = (m0:16)x(n0:16).  No barriers: all loads pipeline freely.
__global__ __launch_bounds__(64) void k_fc1(const float* __restrict__ se, const float* __restrict__ te,
                                            const ushort* __restrict__ WstT, const float* __restrict__ bias,
                                            ushort* __restrict__ stb) {
    int bid = blockIdx.x;
    int m0 = (bid >> 4) * 16, n0 = (bid & 15) * 32;
    int lane = threadIdx.x;
    int lhi = lane >> 4, llo = lane & 15;
    f32x4 acc[2] = {};
    #pragma unroll
    for (int kk = 0; kk < 20; kk++) {
        int kb = kk * 32 + lhi * 8;
        const float* xr = (kb < 512) ? se + (size_t)(m0 + llo) * 512 + kb
                                     : te + (size_t)(m0 + llo) * 128 + (kb - 512);
        float4 x0 = *(const float4*)xr;
        float4 x1 = *(const float4*)(xr + 4);
        bf16x8 bfr = cvt8(x0, x1);
        #pragma unroll
        for (int nt = 0; nt < 2; nt++) {
            bf16x8 afr = *(const bf16x8*)(WstT + (size_t)(n0 + nt * 16 + llo) * 640 + kb);
            acc[nt] = __builtin_amdgcn_mfma_f32_16x16x32_bf16(afr, bfr, acc[nt], 0, 0, 0);
        }
    }
    // D: col(=m)=llo, row(=n)=lhi*4+r
    #pragma unroll
    for (int nt = 0; nt < 2; nt++) {
        int n = n0 + nt * 16 + lhi * 4;
        float4 bb = *(const float4*)(bias + n);
        ushort4 o;
        o.x = f2bf(fmaxf(acc[nt][0] + bb.x, 0.f));
        o.y = f2bf(fmaxf(acc[nt][1] + bb.y, 0.f));
        o.z = f2bf(fmaxf(acc[nt][2] + bb.z, 0.f));
        o.w = f2bf(fmaxf(acc[nt][3] + bb.w, 0.f));
        *(ushort4*)(stb + (size_t)(m0 + llo) * 512 + n) = o;
    }
}

// LNG = stb @ W_q + b_q (fp32 out).  LDS-free MFMA, 1 wave/block, 16m x 32n tile.
// grid (65, 16): n0 = bx*32 (2056 edge guarded), m0 = by*16.
__global__ __launch_bounds__(64) void k_fc2(const ushort* __restrict__ stb, const ushort* __restrict__ WqT,
                                            const float* __restrict__ bias, float* __restrict__ LNG) {
    int n0 = blockIdx.x * 32, m0 = blockIdx.y * 16;
    int lane = threadIdx.x;
    int lhi = lane >> 4, llo = lane & 15;
    f32x4 acc[2] = {};
    #pragma unroll
    for (int kk = 0; kk < 16; kk++) {
        int kb = kk * 32 + lhi * 8;
        bf16x8 bfr = *(const bf16x8*)(stb + (size_t)(m0 + llo) * 512 + kb);
        #pragma unroll
        for (int nt = 0; nt < 2; nt++) {
            int n = n0 + nt * 16 + llo; if (n > 2055) n = 2055;
            bf16x8 afr = *(const bf16x8*)(WqT + (size_t)n * 512 + kb);
            acc[nt] = __builtin_amdgcn_mfma_f32_16x16x32_bf16(afr, bfr, acc[nt], 0, 0, 0);
        }
    }
    #pragma unroll
    for (int nt = 0; nt < 2; nt++) {
        int n = n0 + nt * 16 + lhi * 4;
        if (n < 2056) {
            float4 bb = *(const float4*)(bias + n);
            f32x4 v = {acc[nt][0] + bb.x, acc[nt][1] + bb.y, acc[nt][2] + bb.z, acc[nt][3] + bb.w};
            *(f32x4*)(LNG + (size_t)(m0 + llo) * 2056 + n) = v;
        }
    }
}

// Per active arg t: split LNG row -> GQB(bf16) / none-logit (direct to d_out);
// qk[t]=W_key@q_local, qb[t]=b_key.q_local.  Rows t in [total,2048) get zero GQB.
__global__ __launch_bounds__(256) void k_extract(const int* __restrict__ W, const float* __restrict__ LNG,
                                                 const float* __restrict__ Wkey, const float* __restrict__ bkey,
                                                 ushort* __restrict__ GQB, float* __restrict__ out, int L,
                                                 float* __restrict__ QK, float* __restrict__ QB) {
    int t = blockIdx.x;
    int total = W[O_TOT];
    int tid = threadIdx.x;
    if (t >= total) {
        if (tid >= 128) GQB[t * 128 + tid - 128] = 0;
        return;
    }
    int b = W[O_AB + t], slot = W[O_SL + t];
    const float* base = LNG + b * LNGW + slot * DIMQ;
    __shared__ float sl[CTXD];
    if (tid < 128) {
        sl[tid] = base[tid];
    } else {
        int d = tid - 128;
        GQB[t * 128 + d] = f2bf(base[129 + d]);
    }
    if (tid == 0) {
        int np = W[O_NP];
        out[np + t] = (float)t;
        out[L + np + t] = base[128];
    }
    __syncthreads();
    float acc = 0.f;
    const float* wr = Wkey + tid * 128;
    #pragma unroll
    for (int k = 0; k < 128; k += 4) {
        float4 w4 = *(const float4*)(wr + k);
        acc += w4.x * sl[k] + w4.y * sl[k + 1] + w4.z * sl[k + 2] + w4.w * sl[k + 3];
    }
    QK[t * 256 + tid] = acc;
    if (tid == 0) {
        float qb = 0.f;
        for (int k = 0; k < 128; k++) qb += bkey[k] * sl[k];
        QB[t] = qb;
    }
}

// gather + L2-normalize definition embeddings -> bf16 table in ws
__global__ __launch_bounds__(256) void k_gk(const int* __restrict__ gctx, const float* __restrict__ emb,
                                            ushort* __restrict__ gkb) {
    int tid = threadIdx.x;
    int g = blockIdx.x * 8 + (tid >> 5);
    int row = gctx[g];
    int c = tid & 31;
    float4 e = *(const float4*)(emb + (size_t)row * 128 + c * 4);
    float ss = e.x * e.x + e.y * e.y + e.z * e.z + e.w * e.w;
    #pragma unroll
    for (int off = 1; off < 32; off <<= 1) ss += __shfl_xor(ss, off);
    float sc = 1.f / (1e-7f + sqrtf(ss));
    ushort4 o;
    o.x = f2bf(e.x * sc); o.y = f2bf(e.y * sc); o.z = f2bf(e.z * sc); o.w = f2bf(e.w * sc);
    *(ushort4*)(gkb + (size_t)g * 128 + c * 4) = o;
}

// local logits: 4-lane groups, 16 rows/wave, QK staged in LDS (broadcast reads).
__global__ __launch_bounds__(256) void k_pairs(const int* __restrict__ W, const float* __restrict__ ctxv,
                                               const float* __restrict__ QK, const float* __restrict__ QB,
                                               float* __restrict__ out, int L) {
    int b = blockIdx.x >> 2, sub = blockIdx.x & 3;
    int as = W[O_AS + b];
    int cnt = W[O_AS + b + 1] - as;
    if (cnt == 0) return;
    int cs = W[O_CS + b];
    int len = W[O_CS + b + 1] - cs;
    int j0 = (len * sub) >> 2, j1 = (len * (sub + 1)) >> 2;
    __shared__ float sqk[MAXA][256];
    __shared__ float sqb[MAXA];
    __shared__ int sps[MAXA];
    int tid = threadIdx.x;
    for (int i = tid; i < cnt * 256; i += 256) sqk[i >> 8][i & 255] = QK[(as + (i >> 8)) * 256 + (i & 255)];
    if (tid < cnt) { sqb[tid] = QB[as + tid]; sps[tid] = W[O_PS + as + tid]; }
    __syncthreads();
    int wv = tid >> 6, lane = tid & 63;
    int g = lane >> 2, il = lane & 3;
    for (int jb = j0 + wv * 16; jb < j1; jb += 64) {
        int j = jb + g;
        bool ok = (j < j1);
        int row = cs + (ok ? j : j1 - 1);
        const float* xr = ctxv + (size_t)row * 256;
        float acc[MAXA] = {};
        #pragma unroll
        for (int c = 0; c < 16; c++) {
            float4 x4 = *(const float4*)(xr + c * 16 + il * 4);
            #pragma unroll
            for (int a = 0; a < MAXA; a++) {
                if (a < cnt) {
                    float4 q4 = *(const float4*)(&sqk[a][c * 16 + il * 4]);
                    acc[a] += x4.x * q4.x + x4.y * q4.y + x4.z * q4.z + x4.w * q4.w;
                }
            }
        }
        #pragma unroll
        for (int a = 0; a < MAXA; a++) {
            if (a < cnt) {
                float p = acc[a];
                p += __shfl_xor(p, 1);
                p += __shfl_xor(p, 2);
                if (il == 0 && ok) {
                    out[sps[a] + j] = (float)(as + a);
                    out[L + sps[a] + j] = p + sqb[a];
                }
            }
        }
    }
}

// global logits via bf16 MFMA.  Block = 128 defs x 256 args, 4 waves x 32 defs.
// GKB A-frags register-resident; GQB B-frags prefetched one 32-arg chunk ahead.
// Double-buffered LDS epilogue: ONE barrier per chunk; stores issued at window start
// so they drain under the next chunk's MFMA.  LDS 33.8KB -> 4 blocks/CU.
__global__ __launch_bounds__(256) void k_gglob(const int* __restrict__ W, const ushort* __restrict__ GQB,
                                               const ushort* __restrict__ GKB, float* __restrict__ out, int L) {
    __shared__ float tile[2][32][132];
    int total = W[O_TOT], np = W[O_NP];
    int t0 = blockIdx.y * 256;
    if (t0 >= total) return;
    float* outi = out + np + total;
    float* outv = out + L + np + total;
    int g0 = blockIdx.x * 128;
    int tid = threadIdx.x, wv = tid >> 6, lane = tid & 63;
    int lhi = lane >> 4, llo = lane & 15;
    int gw = wv * 32;
    bf16x8 afr[2][4];
    #pragma unroll
    for (int nt = 0; nt < 2; nt++) {
        int g = g0 + gw + nt * 16 + llo;
        const ushort* ap = GKB + (size_t)(g < DEFN ? g : DEFN - 1) * 128 + lhi * 8;
        #pragma unroll
        for (int kk = 0; kk < 4; kk++)
            afr[nt][kk] = *(const bf16x8*)(ap + kk * 32);
    }
    int nchunk = (total - t0 + 31) >> 5;
    if (nchunk > 8) nchunk = 8;
    bf16x8 bfr[2][4];
    #pragma unroll
    for (int ts = 0; ts < 2; ts++)
        #pragma unroll
        for (int kk = 0; kk < 4; kk++)
            bfr[ts][kk] = *(const bf16x8*)(GQB + (size_t)(t0 + ts * 16 + llo) * 128 + kk * 32 + lhi * 8);
    int half = lane >> 5, cc = (lane & 31) * 4;
    bool gok = (g0 + cc) < DEFN;
    for (int tc = 0; tc < nchunk; tc++) {
        int t1 = t0 + tc * 32;
        int buf = tc & 1;
        f32x4 acc[2][2] = {};
        #pragma unroll
        for (int nt = 0; nt < 2; nt++)
            #pragma unroll
            for (int kk = 0; kk < 4; kk++)
                #pragma unroll
                for (int ts = 0; ts < 2; ts++)
                    acc[ts][nt] = __builtin_amdgcn_mfma_f32_16x16x32_bf16(afr[nt][kk], bfr[ts][kk], acc[ts][nt], 0, 0, 0);
        if (tc + 1 < nchunk) {
            int t2 = t1 + 32;
            #pragma unroll
            for (int ts = 0; ts < 2; ts++)
                #pragma unroll
                for (int kk = 0; kk < 4; kk++)
                    bfr[ts][kk] = *(const bf16x8*)(GQB + (size_t)(t2 + ts * 16 + llo) * 128 + kk * 32 + lhi * 8);
        }
        // D: col(=arg t)=llo, row(=def g)=lhi*4+reg  -> LDS (buf)
        #pragma unroll
        for (int nt = 0; nt < 2; nt++)
            #pragma unroll
            for (int ts = 0; ts < 2; ts++)
                *(f32x4*)&tile[buf][ts * 16 + llo][gw + nt * 16 + lhi * 4] = acc[ts][nt];
        __syncthreads();
        // stores: 512B contiguous per 32 lanes; drain overlaps next chunk's MFMA
        #pragma unroll
        for (int rp = 0; rp < 4; rp++) {
            int r = wv * 8 + rp * 2 + half;
            int t = t1 + r;
            if (t < total && gok) {
                size_t rb = (size_t)t * DEFN + g0 + cc;
                *(f32x4*)(outv + rb) = *(const f32x4*)&tile[buf][r][cc];
                float ft = (float)t;
                f32x4 fi = {ft, ft, ft, ft};
                *(f32x4*)(outi + rb) = fi;
            }
        }
    }
}

extern "C" void kernel_launch(void* const* d_in, const int* in_sizes, int n_in,
                              void* d_out, int out_size, void* d_ws, size_t ws_size,
                              hipStream_t stream) {
    const float* ctx_vals  = (const float*)d_in[0];
    const float* state_emb = (const float*)d_in[1];
    const float* tactic    = (const float*)d_in[2];
    const float* emb       = (const float*)d_in[3];
    const float* W_key     = (const float*)d_in[4];
    const float* b_key     = (const float*)d_in[5];
    const float* W_st      = (const float*)d_in[6];
    const float* b_st      = (const float*)d_in[7];
    const float* W_q       = (const float*)d_in[8];
    const float* b_q       = (const float*)d_in[9];
    const int* ctx_ids     = (const int*)d_in[10];
    const int* arg_cnt     = (const int*)d_in[11];
    const int* gctx        = (const int*)d_in[12];
    int n_ctx = in_sizes[10];
    int L = out_size / 2;
    int* W  = (int*)d_ws;
    float* F = (float*)d_ws;
    float* out = (float*)d_out;

    k_bounds<<<dim3((n_ctx + 255) / 256), dim3(256), 0, stream>>>(ctx_ids, n_ctx, W);
    k_scan<<<dim3(1), dim3(256), 0, stream>>>(arg_cnt, W);
    k_trans<<<dim3(16, 20), dim3(256), 0, stream>>>(W_st, (ushort*)(F + F_WST), 640, 512);
    k_trans<<<dim3(65, 16), dim3(256), 0, stream>>>(W_q, (ushort*)(F + F_WQT), 512, 2056);
    k_fc1<<<dim3(256), dim3(64), 0, stream>>>(state_emb, tactic, (ushort*)(F + F_WST), b_st,
                                              (ushort*)(F + F_STB));
    k_fc2<<<dim3(65, 16), dim3(64), 0, stream>>>((ushort*)(F + F_STB), (ushort*)(F + F_WQT), b_q,
                                                 F + F_LNG);
    k_extract<<<dim3(2048), dim3(256), 0, stream>>>(W, F + F_LNG, W_key, b_key,
                                                    (ushort*)(F + F_GQB), out, L, F + F_QK, F + F_QB);
    k_pairs<<<dim3(1024), dim3(256), 0, stream>>>(W, ctx_vals, F + F_QK, F + F_QB, out, L);
    k_gk<<<dim3(2500), dim3(256), 0, stream>>>(gctx, emb, (ushort*)(F + F_GKB));
    k_gglob<<<dim3(157, 8), dim3(256), 0, stream>>>(W, (ushort*)(F + F_GQB), (ushort*)(F + F_GKB), out, L);
}